// Round 3
// baseline (821.309 us; speedup 1.0000x reference)
//
#include <hip/hip_runtime.h>
#include <math.h>

// Problem constants
#define HW 65536          // 256*256
#define NPAD 258          // padded spatial dim

typedef short bf16x8 __attribute__((ext_vector_type(8)));
typedef float f32x4  __attribute__((ext_vector_type(4)));

// Workspace layout (bytes)
#define O_COUNTS 0            // 12 * 32 ints = 1536 B
#define O_W2C    2048         // 8 * 16 floats = 512 B
#define O_WT     4096         // 2 convs * 36864 bf16 = 147456 B  [cv][h][tap][q][co][8ci]
#define O_META   151552       // 12 * 65536 ints = 3 MiB
#define O_FUSED  3297280      // 8*258*258*64 bf16 = 68,161,536 B
#define O_X1     71458816     // same size

// Conv LDS: ONE half-channel tile: 6 rows x 66 px x 64 B (32 ci).
// Row stride 4240 B (4224 + 16 pad). 25440 B total -> 6 blocks/CU resident.
#define HROWB   4224              // 66 px * 64 B
#define HROWSTR 4240
#define HBUFB   (6 * HROWSTR)     // 25440 B

__device__ __forceinline__ unsigned short f2bf(float f) {
    unsigned int u = __float_as_uint(f);
    u += 0x7FFFu + ((u >> 16) & 1u);   // round-to-nearest-even
    return (unsigned short)(u >> 16);
}

// Fast erf-based GELU (Abramowitz-Stegun 7.1.26, |err_erf| <= 1.5e-7).
__device__ __forceinline__ float gelu_fast(float v) {
    float x  = v * 0.70710678118654752f;
    float ax = fabsf(x);
    float t  = __builtin_amdgcn_rcpf(fmaf(0.3275911f, ax, 1.0f));
    float p  = fmaf(t, 1.061405429f, -1.453152027f);
    p = fmaf(t, p, 1.421413741f);
    p = fmaf(t, p, -0.284496736f);
    p = fmaf(t, p, 0.254829592f);
    p = p * t;
    float e   = __expf(-x * x);
    float era = fmaf(-p, e, 1.0f);
    float er  = copysignf(era, x);
    return 0.5f * v * (1.0f + er);
}

// ---------------------------------------------------------------------------
// Prep: invert extrinsics, build bf16 weight fragment image [h][tap][q][co][8ci],
// zero padded-buffer borders, zero counts
// ---------------------------------------------------------------------------
__global__ __launch_bounds__(256) void prep_kernel(
    const float* __restrict__ extr, const float* __restrict__ w1,
    const float* __restrict__ w2, float* __restrict__ w2c,
    unsigned short* __restrict__ wT, unsigned short* __restrict__ fusedP,
    unsigned short* __restrict__ x1P, int* __restrict__ counts)
{
    int tid = blockIdx.x * blockDim.x + threadIdx.x;
    int nth = gridDim.x * blockDim.x;

    if (blockIdx.x == 0) {
        if (threadIdx.x < 8) {
            float a[4][8];
            const float* E = extr + threadIdx.x * 16;
            for (int r = 0; r < 4; r++)
                for (int c = 0; c < 4; c++) {
                    a[r][c] = E[r*4 + c];
                    a[r][4+c] = (r == c) ? 1.0f : 0.0f;
                }
            for (int col = 0; col < 4; col++) {
                int piv = col; float bm = fabsf(a[col][col]);
                for (int r = col+1; r < 4; r++) {
                    float v = fabsf(a[r][col]);
                    if (v > bm) { bm = v; piv = r; }
                }
                if (piv != col)
                    for (int c = 0; c < 8; c++) { float t = a[col][c]; a[col][c] = a[piv][c]; a[piv][c] = t; }
                float f = 1.0f / a[col][col];
                for (int c = 0; c < 8; c++) a[col][c] *= f;
                for (int r = 0; r < 4; r++) if (r != col) {
                    float f2 = a[r][col];
                    for (int c = 0; c < 8; c++) a[r][c] -= f2 * a[col][c];
                }
            }
            float* O = w2c + threadIdx.x * 16;
            for (int r = 0; r < 4; r++)
                for (int c = 0; c < 4; c++) O[r*4+c] = a[r][4+c];
        }
    }

    // Zero padded count slots (12 * 32 ints)
    for (int i = tid; i < 384; i += nth) counts[i] = 0;

    // Weight fragment image: 2 convs * [h2][tap9][q4][co64][j8]
    for (int e = tid; e < 73728; e += nth) {
        int t = e;
        int j  = t & 7;  t >>= 3;
        int co = t & 63; t >>= 6;
        int q  = t & 3;  t >>= 2;
        int tap = t % 9; t /= 9;
        int h  = t & 1;  int cv = t >> 1;
        int ci = h*32 + q*8 + j;
        int ky = tap / 3, kx = tap % 3;
        const float* wsrc = cv ? w2 : w1;
        float v = wsrc[((co*64 + ci)*3 + ky)*3 + kx];
        wT[cv*36864 + ((((h*9 + tap)*4 + q)*64 + co)*8 + j)] = f2bf(v);
    }

    // Zero borders of both padded buffers
    for (int u = tid; u < 2*8*1028*8; u += nth) {
        int t = u;
        int ch   = t & 7;    t >>= 3;
        int cell = t % 1028; t /= 1028;
        int n    = t & 7;    int buf = t >> 3;
        int y, x;
        if      (cell < 258) { y = 0;   x = cell; }
        else if (cell < 516) { y = 257; x = cell - 258; }
        else if (cell < 772) { y = cell - 516 + 1; x = 0; }
        else                 { y = cell - 772 + 1; x = 257; }
        unsigned short* p = (buf ? x1P : fusedP) +
            (((size_t)(n*NPAD + y)*NPAD + x)*64 + ch*8);
        *reinterpret_cast<uint4*>(p) = make_uint4(0u, 0u, 0u, 0u);
    }
}

// ---------------------------------------------------------------------------
// Projection: per (b, j->k) pair, compute mask|idx per point + valid counts.
// ---------------------------------------------------------------------------
__global__ __launch_bounds__(256) void proj_kernel(
    const float* __restrict__ means, const float* __restrict__ intr,
    const float* __restrict__ w2c, int* __restrict__ meta,
    int* __restrict__ counts)
{
    const int jt[6] = {0,1,1,2,2,3};
    const int kt[6] = {1,0,2,1,3,2};
    int s = blockIdx.y;            // 0..11
    int b = s / 6, p = s % 6;
    int j = jt[p], k = kt[p];
    int i = blockIdx.x * 256 + threadIdx.x;

    __shared__ int bcnt;
    if (threadIdx.x == 0) bcnt = 0;
    __syncthreads();

    const float* mp = means + ((size_t)(b*4 + j)*HW + i)*3;
    float x = mp[0], y = mp[1], z = mp[2];
    const float* M = w2c + (b*4 + k)*16;
    const float* I = intr + (b*4 + k)*9;

    float cx = fmaf(M[2],  z, fmaf(M[1], y, M[0]*x)) + M[3];
    float cy = fmaf(M[6],  z, fmaf(M[5], y, M[4]*x)) + M[7];
    float cz = fmaf(M[10], z, fmaf(M[9], y, M[8]*x)) + M[11];

    bool vz = cz > 1e-8f;
    float zi = cz + 1e-8f;
    float sx = cx / zi, sy = cy / zi, sz = cz / zi;
    float nx = fmaf(I[2], sz, fmaf(I[1], sy, I[0]*sx));
    float ny = fmaf(I[5], sz, fmaf(I[4], sy, I[3]*sx));

    int px = (int)floorf(nx * 256.0f);
    int py = (int)floorf(ny * 256.0f);
    bool mask = (nx >= 0.0f) && (nx < 1.0f) && (ny >= 0.0f) && (ny < 1.0f) && vz;
    int pxc = min(max(px, 0), 255);
    int pyc = min(max(py, 0), 255);
    int idx = pyc*256 + pxc;
    meta[(size_t)s*HW + i] = idx | (mask ? (int)0x80000000 : 0);

    unsigned long long bal = __ballot(mask ? 1 : 0);
    if ((threadIdx.x & 63) == 0)
        atomicAdd(&bcnt, (int)__popcll(bal));
    __syncthreads();
    if (threadIdx.x == 0)
        atomicAdd(counts + s*32, bcnt);
}

// ---------------------------------------------------------------------------
// Fusion: acc = feats_j + sum_k scale_k * masked_gather(feats_k); /norm; bf16
// ---------------------------------------------------------------------------
__global__ __launch_bounds__(256) void fuse_kernel(
    const float* __restrict__ feats, const int* __restrict__ meta,
    const int* __restrict__ counts, unsigned short* __restrict__ fusedP)
{
    const int nsl[4]    = {1, 2, 2, 1};
    const int slt[4][2] = {{0,0},{1,2},{3,4},{5,5}};
    const int kvw[4][2] = {{1,1},{0,2},{1,3},{2,2}};

    int bj = blockIdx.y;           // n = b*4 + j
    int b = bj >> 2, j = bj & 3;
    int pt = blockIdx.x * 16 + (threadIdx.x >> 4);
    int cg = threadIdx.x & 15;

    const float4* fj = reinterpret_cast<const float4*>(
        feats + ((size_t)bj*HW + pt)*64) + cg;
    float4 acc = *fj;
    float norm = 1.0f;
    int ns = nsl[j];
    for (int e = 0; e < 2; e++) {
        if (e < ns) {
            int p = slt[j][e], k = kvw[j][e];
            int s = b*6 + p;
            float scale = 0.1f * (float)counts[s*32] / 65536.0f;
            int mt = meta[(size_t)s*HW + pt];
            if (mt < 0) {
                int idx = mt & 0xFFFF;
                const float4* g = reinterpret_cast<const float4*>(
                    feats + ((size_t)(b*4 + k)*HW + idx)*64) + cg;
                float4 gv = *g;
                acc.x += scale * gv.x; acc.y += scale * gv.y;
                acc.z += scale * gv.z; acc.w += scale * gv.w;
            }
            norm += scale;
        }
    }
    float ox = acc.x / norm, oy = acc.y / norm;
    float oz = acc.z / norm, ow = acc.w / norm;

    int yy = pt >> 8, xx = pt & 255;
    unsigned short* op = fusedP +
        (((size_t)bj*NPAD + (yy+1))*NPAD + (xx+1))*64 + cg*4;
    ushort4 o = make_ushort4(f2bf(ox), f2bf(oy), f2bf(oz), f2bf(ow));
    *reinterpret_cast<ushort4*>(op) = o;
}

// ---------------------------------------------------------------------------
// 3x3 conv: block = 256 thr (4 waves), tile = 4 output rows x 64 px x 64 co.
// Channels split into 2 halves of 32 ci; ONE 25.4 KB LDS buffer used twice:
//   stage(h0) -> sync -> compute 9 taps -> sync -> stage(h1) -> sync -> compute
// Small LDS -> 6 resident blocks/CU; the per-half barrier drain is hidden by
// 6-way inter-block overlap (TLP), with round-1-level register pressure
// (__launch_bounds__(256,6) pins VGPR <= 85).
//
// Half-tile swizzle: 64 B/px = 4 chunks of 16 B; LDS slot (px,c) holds global
// chunk c ^ ((px>>1)&3) -> ds_read_b128 by 64 lanes is a free 2-way pattern.
// Staging keeps LDS dest linear (global_load_lds requirement), pre-swizzles
// the per-lane GLOBAL source address (involution, both-sides rule).
// MFMA operands swapped (weights=A, pixels=B): lane's D holds 4 contiguous
// co per px -> vectorized 8B/16B stores.
// ---------------------------------------------------------------------------
template<int MODE>
__global__ __launch_bounds__(256, 6) void conv_kernel(
    const unsigned short* __restrict__ in, const unsigned short* __restrict__ wT,
    const float* __restrict__ bias, void* __restrict__ outp)
{
    __shared__ unsigned short smem[HBUFB / 2];   // 25440 B

    int n = blockIdx.z;
    int y0 = blockIdx.y * 4;       // first output row (unpadded)
    int X0 = blockIdx.x * 64;      // first output px (unpadded)
    int w  = threadIdx.x >> 6;     // wave id: output row y0+w
    int lane = threadIdx.x & 63;
    int m = lane & 15, q = lane >> 4;

    // Staging per-lane source offsets (relative to a (row, h) strip base).
    // Main 4 KB: load i, lane l covers LDS chunk d=i*64+l -> px=d>>2, c=d&3;
    // source chunk = c ^ s(px), s(px)=(px>>1)&3:
    int srcl = ((lane >> 2) * 128) + ((((lane & 3) ^ ((lane >> 3) & 3)) & 3) << 4);
    // Tail (px 64,65 = 8 chunks, lanes 0..7, s(px)=0 there):
    int tsrcl = 8192 + ((lane >> 2) * 128) + ((lane & 3) << 4);

    // ds_read per-lane bases (one per dx; q fixed per lane so XOR collapses).
    // s(px) for px = Mt*16 + m + dx equals ((m+dx)>>1)&3 (16 = 0 mod 4 after >>1).
    int vb[3];
#pragma unroll
    for (int dx = 0; dx < 3; dx++)
        vb[dx] = w*HROWSTR + m*64 + (((q ^ (((m + dx) >> 1) & 3)) & 3) << 4);

    f32x4 acc[4][4];
#pragma unroll
    for (int a = 0; a < 4; a++)
#pragma unroll
        for (int bq = 0; bq < 4; bq++)
            acc[a][bq] = (f32x4){0.f, 0.f, 0.f, 0.f};

#pragma unroll
    for (int h = 0; h < 2; h++) {
        if (h) __syncthreads();    // all waves done reading half 0

        // Stage half-channel h of 6 padded rows [y0..y0+5] x px [X0..X0+65]
        const char* gb = (const char*)in +
            (((size_t)(n*NPAD) + y0) * NPAD + X0) * 128 + h*64;
        for (int ri = w; ri < 6; ri += 4) {
            const char* g = gb + (size_t)ri * (NPAD*128);
            char* l = (char*)smem + ri*HROWSTR;
#pragma unroll
            for (int i = 0; i < 4; i++)
                __builtin_amdgcn_global_load_lds(
                    (const __attribute__((address_space(1))) unsigned int*)(g + i*2048 + srcl),
                    (__attribute__((address_space(3))) unsigned int*)(l + i*1024 + (size_t)lane*16),
                    16, 0, 0);
            if (lane < 8)
                __builtin_amdgcn_global_load_lds(
                    (const __attribute__((address_space(1))) unsigned int*)(g + tsrcl),
                    (__attribute__((address_space(3))) unsigned int*)(l + 4096 + (size_t)lane*16),
                    16, 0, 0);
        }
        __syncthreads();

        // 9 taps of this half (K=32 per tap -> 1 MFMA per (Mt,Nt))
        const char* wb = (const char*)wT + h*36864 + q*1024 + m*16;
#pragma unroll
        for (int tap = 0; tap < 9; tap++) {
            int dy = tap/3, dx = tap%3;
            bf16x8 av[4], bv[4];
#pragma unroll
            for (int Mt = 0; Mt < 4; Mt++)
                av[Mt] = *reinterpret_cast<const bf16x8*>(
                    (const char*)smem + vb[dx] + dy*HROWSTR + Mt*1024 + dx*64);
#pragma unroll
            for (int Nt = 0; Nt < 4; Nt++)
                bv[Nt] = *reinterpret_cast<const bf16x8*>(wb + tap*4096 + Nt*256);
            // Swapped operands: D[row=co-local][col=px-local].
#pragma unroll
            for (int Mt = 0; Mt < 4; Mt++)
#pragma unroll
                for (int Nt = 0; Nt < 4; Nt++)
                    acc[Mt][Nt] = __builtin_amdgcn_mfma_f32_16x16x32_bf16(
                        bv[Nt], av[Mt], acc[Mt][Nt], 0, 0, 0);
        }
    }

    // Epilogue. D layout: col(px-local)=m, row(co-local)=q*4+r.
    int yout = y0 + w;
#pragma unroll
    for (int Nt = 0; Nt < 4; Nt++) {
        float4 bs = *reinterpret_cast<const float4*>(bias + Nt*16 + q*4);
        int co0 = Nt*16 + q*4;
#pragma unroll
        for (int Mt = 0; Mt < 4; Mt++) {
            int px = X0 + Mt*16 + m;
            float v0 = acc[Mt][Nt][0] + bs.x;
            float v1 = acc[Mt][Nt][1] + bs.y;
            float v2 = acc[Mt][Nt][2] + bs.z;
            float v3 = acc[Mt][Nt][3] + bs.w;
            if (MODE == 1) {
                v0 = gelu_fast(v0); v1 = gelu_fast(v1);
                v2 = gelu_fast(v2); v3 = gelu_fast(v3);
                unsigned short* o = (unsigned short*)outp +
                    ((size_t)(n*NPAD + yout + 1)*NPAD + (px + 1))*64 + co0;
                ushort4 pk = make_ushort4(f2bf(v0), f2bf(v1), f2bf(v2), f2bf(v3));
                *reinterpret_cast<ushort4*>(o) = pk;
            } else {
                float* o = (float*)outp +
                    ((size_t)(n*256 + yout)*256 + px)*64 + co0;
                *reinterpret_cast<float4*>(o) = make_float4(v0, v1, v2, v3);
            }
        }
    }
}

extern "C" void kernel_launch(void* const* d_in, const int* in_sizes, int n_in,
                              void* d_out, int out_size, void* d_ws, size_t ws_size,
                              hipStream_t stream)
{
    const float* means = (const float*)d_in[0];
    const float* feats = (const float*)d_in[2];
    const float* intr  = (const float*)d_in[3];
    const float* extr  = (const float*)d_in[4];
    const float* w1    = (const float*)d_in[5];
    const float* b1    = (const float*)d_in[6];
    const float* w2    = (const float*)d_in[7];
    const float* b2    = (const float*)d_in[8];

    char* ws = (char*)d_ws;
    int*            counts = (int*)(ws + O_COUNTS);
    float*          w2c    = (float*)(ws + O_W2C);
    unsigned short* wT     = (unsigned short*)(ws + O_WT);
    int*            meta   = (int*)(ws + O_META);
    unsigned short* fusedP = (unsigned short*)(ws + O_FUSED);
    unsigned short* x1P    = (unsigned short*)(ws + O_X1);

    prep_kernel<<<dim3(96), dim3(256), 0, stream>>>(
        extr, w1, w2, w2c, wT, fusedP, x1P, counts);
    proj_kernel<<<dim3(256, 12), dim3(256), 0, stream>>>(
        means, intr, w2c, meta, counts);
    fuse_kernel<<<dim3(4096, 8), dim3(256), 0, stream>>>(
        feats, meta, counts, fusedP);
    conv_kernel<1><<<dim3(4, 64, 8), dim3(256), 0, stream>>>(
        fusedP, wT, b1, (void*)x1P);
    conv_kernel<2><<<dim3(4, 64, 8), dim3(256), 0, stream>>>(
        x1P, wT + 36864, b2, d_out);
}

// Round 4
// 397.777 us; speedup vs baseline: 2.0647x; 2.0647x over previous
//
#include <hip/hip_runtime.h>
#include <math.h>

// Problem constants
#define HW 65536          // 256*256
#define NPAD 258          // padded spatial dim

typedef short bf16x8 __attribute__((ext_vector_type(8)));
typedef float f32x4  __attribute__((ext_vector_type(4)));

// Workspace layout (bytes)
#define O_COUNTS 0            // 12 * 32 ints = 1536 B
#define O_W2C    2048         // 8 * 16 floats = 512 B
#define O_WT     4096         // 2 convs * 36864 bf16 = 147456 B  [cv][h][tap][q][co][8ci]
#define O_META   151552       // 12 * 65536 ints = 3 MiB
#define O_FUSED  3297280      // 8*258*258*64 bf16 = 68,161,536 B
#define O_X1     71458816     // same size

// Conv LDS: ONE half-channel tile: 6 rows x 66 px x 64 B (32 ci).
// Row stride 4240 B (4224 + 16 pad). 25440 B total -> 6 blocks/CU resident.
#define HROWB   4224              // 66 px * 64 B
#define HROWSTR 4240
#define HBUFB   (6 * HROWSTR)     // 25440 B

__device__ __forceinline__ unsigned short f2bf(float f) {
    unsigned int u = __float_as_uint(f);
    u += 0x7FFFu + ((u >> 16) & 1u);   // round-to-nearest-even
    return (unsigned short)(u >> 16);
}

// Fast erf-based GELU (Abramowitz-Stegun 7.1.26, |err_erf| <= 1.5e-7).
__device__ __forceinline__ float gelu_fast(float v) {
    float x  = v * 0.70710678118654752f;
    float ax = fabsf(x);
    float t  = __builtin_amdgcn_rcpf(fmaf(0.3275911f, ax, 1.0f));
    float p  = fmaf(t, 1.061405429f, -1.453152027f);
    p = fmaf(t, p, 1.421413741f);
    p = fmaf(t, p, -0.284496736f);
    p = fmaf(t, p, 0.254829592f);
    p = p * t;
    float e   = __expf(-x * x);
    float era = fmaf(-p, e, 1.0f);
    float er  = copysignf(era, x);
    return 0.5f * v * (1.0f + er);
}

// ---------------------------------------------------------------------------
// Prep: invert extrinsics, build bf16 weight fragment image [h][tap][q][co][8ci],
// zero padded-buffer borders, zero counts
// ---------------------------------------------------------------------------
__global__ __launch_bounds__(256) void prep_kernel(
    const float* __restrict__ extr, const float* __restrict__ w1,
    const float* __restrict__ w2, float* __restrict__ w2c,
    unsigned short* __restrict__ wT, unsigned short* __restrict__ fusedP,
    unsigned short* __restrict__ x1P, int* __restrict__ counts)
{
    int tid = blockIdx.x * blockDim.x + threadIdx.x;
    int nth = gridDim.x * blockDim.x;

    if (blockIdx.x == 0) {
        if (threadIdx.x < 8) {
            float a[4][8];
            const float* E = extr + threadIdx.x * 16;
            for (int r = 0; r < 4; r++)
                for (int c = 0; c < 4; c++) {
                    a[r][c] = E[r*4 + c];
                    a[r][4+c] = (r == c) ? 1.0f : 0.0f;
                }
            for (int col = 0; col < 4; col++) {
                int piv = col; float bm = fabsf(a[col][col]);
                for (int r = col+1; r < 4; r++) {
                    float v = fabsf(a[r][col]);
                    if (v > bm) { bm = v; piv = r; }
                }
                if (piv != col)
                    for (int c = 0; c < 8; c++) { float t = a[col][c]; a[col][c] = a[piv][c]; a[piv][c] = t; }
                float f = 1.0f / a[col][col];
                for (int c = 0; c < 8; c++) a[col][c] *= f;
                for (int r = 0; r < 4; r++) if (r != col) {
                    float f2 = a[r][col];
                    for (int c = 0; c < 8; c++) a[r][c] -= f2 * a[col][c];
                }
            }
            float* O = w2c + threadIdx.x * 16;
            for (int r = 0; r < 4; r++)
                for (int c = 0; c < 4; c++) O[r*4+c] = a[r][4+c];
        }
    }

    // Zero padded count slots (12 * 32 ints)
    for (int i = tid; i < 384; i += nth) counts[i] = 0;

    // Weight fragment image: 2 convs * [h2][tap9][q4][co64][j8]
    for (int e = tid; e < 73728; e += nth) {
        int t = e;
        int j  = t & 7;  t >>= 3;
        int co = t & 63; t >>= 6;
        int q  = t & 3;  t >>= 2;
        int tap = t % 9; t /= 9;
        int h  = t & 1;  int cv = t >> 1;
        int ci = h*32 + q*8 + j;
        int ky = tap / 3, kx = tap % 3;
        const float* wsrc = cv ? w2 : w1;
        float v = wsrc[((co*64 + ci)*3 + ky)*3 + kx];
        wT[cv*36864 + ((((h*9 + tap)*4 + q)*64 + co)*8 + j)] = f2bf(v);
    }

    // Zero borders of both padded buffers
    for (int u = tid; u < 2*8*1028*8; u += nth) {
        int t = u;
        int ch   = t & 7;    t >>= 3;
        int cell = t % 1028; t /= 1028;
        int n    = t & 7;    int buf = t >> 3;
        int y, x;
        if      (cell < 258) { y = 0;   x = cell; }
        else if (cell < 516) { y = 257; x = cell - 258; }
        else if (cell < 772) { y = cell - 516 + 1; x = 0; }
        else                 { y = cell - 772 + 1; x = 257; }
        unsigned short* p = (buf ? x1P : fusedP) +
            (((size_t)(n*NPAD + y)*NPAD + x)*64 + ch*8);
        *reinterpret_cast<uint4*>(p) = make_uint4(0u, 0u, 0u, 0u);
    }
}

// ---------------------------------------------------------------------------
// Projection: per (b, j->k) pair, compute mask|idx per point + valid counts.
// ---------------------------------------------------------------------------
__global__ __launch_bounds__(256) void proj_kernel(
    const float* __restrict__ means, const float* __restrict__ intr,
    const float* __restrict__ w2c, int* __restrict__ meta,
    int* __restrict__ counts)
{
    const int jt[6] = {0,1,1,2,2,3};
    const int kt[6] = {1,0,2,1,3,2};
    int s = blockIdx.y;            // 0..11
    int b = s / 6, p = s % 6;
    int j = jt[p], k = kt[p];
    int i = blockIdx.x * 256 + threadIdx.x;

    __shared__ int bcnt;
    if (threadIdx.x == 0) bcnt = 0;
    __syncthreads();

    const float* mp = means + ((size_t)(b*4 + j)*HW + i)*3;
    float x = mp[0], y = mp[1], z = mp[2];
    const float* M = w2c + (b*4 + k)*16;
    const float* I = intr + (b*4 + k)*9;

    float cx = fmaf(M[2],  z, fmaf(M[1], y, M[0]*x)) + M[3];
    float cy = fmaf(M[6],  z, fmaf(M[5], y, M[4]*x)) + M[7];
    float cz = fmaf(M[10], z, fmaf(M[9], y, M[8]*x)) + M[11];

    bool vz = cz > 1e-8f;
    float zi = cz + 1e-8f;
    float sx = cx / zi, sy = cy / zi, sz = cz / zi;
    float nx = fmaf(I[2], sz, fmaf(I[1], sy, I[0]*sx));
    float ny = fmaf(I[5], sz, fmaf(I[4], sy, I[3]*sx));

    int px = (int)floorf(nx * 256.0f);
    int py = (int)floorf(ny * 256.0f);
    bool mask = (nx >= 0.0f) && (nx < 1.0f) && (ny >= 0.0f) && (ny < 1.0f) && vz;
    int pxc = min(max(px, 0), 255);
    int pyc = min(max(py, 0), 255);
    int idx = pyc*256 + pxc;
    meta[(size_t)s*HW + i] = idx | (mask ? (int)0x80000000 : 0);

    unsigned long long bal = __ballot(mask ? 1 : 0);
    if ((threadIdx.x & 63) == 0)
        atomicAdd(&bcnt, (int)__popcll(bal));
    __syncthreads();
    if (threadIdx.x == 0)
        atomicAdd(counts + s*32, bcnt);
}

// ---------------------------------------------------------------------------
// Fusion: acc = feats_j + sum_k scale_k * masked_gather(feats_k); /norm; bf16
// ---------------------------------------------------------------------------
__global__ __launch_bounds__(256) void fuse_kernel(
    const float* __restrict__ feats, const int* __restrict__ meta,
    const int* __restrict__ counts, unsigned short* __restrict__ fusedP)
{
    const int nsl[4]    = {1, 2, 2, 1};
    const int slt[4][2] = {{0,0},{1,2},{3,4},{5,5}};
    const int kvw[4][2] = {{1,1},{0,2},{1,3},{2,2}};

    int bj = blockIdx.y;           // n = b*4 + j
    int b = bj >> 2, j = bj & 3;
    int pt = blockIdx.x * 16 + (threadIdx.x >> 4);
    int cg = threadIdx.x & 15;

    const float4* fj = reinterpret_cast<const float4*>(
        feats + ((size_t)bj*HW + pt)*64) + cg;
    float4 acc = *fj;
    float norm = 1.0f;
    int ns = nsl[j];
    for (int e = 0; e < 2; e++) {
        if (e < ns) {
            int p = slt[j][e], k = kvw[j][e];
            int s = b*6 + p;
            float scale = 0.1f * (float)counts[s*32] / 65536.0f;
            int mt = meta[(size_t)s*HW + pt];
            if (mt < 0) {
                int idx = mt & 0xFFFF;
                const float4* g = reinterpret_cast<const float4*>(
                    feats + ((size_t)(b*4 + k)*HW + idx)*64) + cg;
                float4 gv = *g;
                acc.x += scale * gv.x; acc.y += scale * gv.y;
                acc.z += scale * gv.z; acc.w += scale * gv.w;
            }
            norm += scale;
        }
    }
    float ox = acc.x / norm, oy = acc.y / norm;
    float oz = acc.z / norm, ow = acc.w / norm;

    int yy = pt >> 8, xx = pt & 255;
    unsigned short* op = fusedP +
        (((size_t)bj*NPAD + (yy+1))*NPAD + (xx+1))*64 + cg*4;
    ushort4 o = make_ushort4(f2bf(ox), f2bf(oy), f2bf(oz), f2bf(ow));
    *reinterpret_cast<ushort4*>(op) = o;
}

// ---------------------------------------------------------------------------
// 3x3 conv: block = 256 thr (4 waves), tile = 4 output rows x 64 px x 64 co.
// Channels split into 2 halves of 32 ci; ONE 25.4 KB LDS buffer used twice:
//   stage(h0) -> sync -> compute 9 taps -> sync -> stage(h1) -> sync -> compute
// 25.4 KB LDS -> 6 resident blocks/CU (LDS is the binder; natural VGPR ~76
// permits it). The per-half barrier drain is hidden by 6-way inter-block
// overlap (TLP). NOTE: no min-waves in __launch_bounds__ — pinning 6 waves/EU
// in round 3 forced VGPR to 40 and spilled the accumulators to scratch
// (FETCH 392 MB, WRITE 856 MB, 3.5x slowdown). Natural allocation already
// fits 6 blocks.
//
// Half-tile swizzle: 64 B/px = 4 chunks of 16 B; LDS slot (px,c) holds global
// chunk c ^ ((px>>1)&3) -> ds_read_b128 by 64 lanes is a free 2-way pattern.
// Staging keeps LDS dest linear (global_load_lds requirement), pre-swizzles
// the per-lane GLOBAL source address (involution, both-sides rule).
// MFMA operands swapped (weights=A, pixels=B): lane's D holds 4 contiguous
// co per px -> vectorized 8B/16B stores.
// ---------------------------------------------------------------------------
template<int MODE>
__global__ __launch_bounds__(256) void conv_kernel(
    const unsigned short* __restrict__ in, const unsigned short* __restrict__ wT,
    const float* __restrict__ bias, void* __restrict__ outp)
{
    __shared__ unsigned short smem[HBUFB / 2];   // 25440 B

    int n = blockIdx.z;
    int y0 = blockIdx.y * 4;       // first output row (unpadded)
    int X0 = blockIdx.x * 64;      // first output px (unpadded)
    int w  = threadIdx.x >> 6;     // wave id: output row y0+w
    int lane = threadIdx.x & 63;
    int m = lane & 15, q = lane >> 4;

    // Staging per-lane source offsets (relative to a (row, h) strip base).
    // Main 4 KB: load i, lane l covers LDS chunk d=i*64+l -> px=d>>2, c=d&3;
    // source chunk = c ^ s(px), s(px)=(px>>1)&3:
    int srcl = ((lane >> 2) * 128) + ((((lane & 3) ^ ((lane >> 3) & 3)) & 3) << 4);
    // Tail (px 64,65 = 8 chunks, lanes 0..7, s(px)=0 there):
    int tsrcl = 8192 + ((lane >> 2) * 128) + ((lane & 3) << 4);

    // ds_read per-lane bases (one per dx; q fixed per lane so XOR collapses).
    // s(px) for px = Mt*16 + m + dx equals ((m+dx)>>1)&3 (16 = 0 mod 4 after >>1).
    int vb[3];
#pragma unroll
    for (int dx = 0; dx < 3; dx++)
        vb[dx] = w*HROWSTR + m*64 + (((q ^ (((m + dx) >> 1) & 3)) & 3) << 4);

    f32x4 acc[4][4];
#pragma unroll
    for (int a = 0; a < 4; a++)
#pragma unroll
        for (int bq = 0; bq < 4; bq++)
            acc[a][bq] = (f32x4){0.f, 0.f, 0.f, 0.f};

#pragma unroll
    for (int h = 0; h < 2; h++) {
        if (h) __syncthreads();    // all waves done reading half 0

        // Stage half-channel h of 6 padded rows [y0..y0+5] x px [X0..X0+65]
        const char* gb = (const char*)in +
            (((size_t)(n*NPAD) + y0) * NPAD + X0) * 128 + h*64;
        for (int ri = w; ri < 6; ri += 4) {
            const char* g = gb + (size_t)ri * (NPAD*128);
            char* l = (char*)smem + ri*HROWSTR;
#pragma unroll
            for (int i = 0; i < 4; i++)
                __builtin_amdgcn_global_load_lds(
                    (const __attribute__((address_space(1))) unsigned int*)(g + i*2048 + srcl),
                    (__attribute__((address_space(3))) unsigned int*)(l + i*1024 + (size_t)lane*16),
                    16, 0, 0);
            if (lane < 8)
                __builtin_amdgcn_global_load_lds(
                    (const __attribute__((address_space(1))) unsigned int*)(g + tsrcl),
                    (__attribute__((address_space(3))) unsigned int*)(l + 4096 + (size_t)lane*16),
                    16, 0, 0);
        }
        __syncthreads();

        // 9 taps of this half (K=32 per tap -> 1 MFMA per (Mt,Nt))
        const char* wb = (const char*)wT + h*36864 + q*1024 + m*16;
#pragma unroll
        for (int tap = 0; tap < 9; tap++) {
            int dy = tap/3, dx = tap%3;
            bf16x8 av[4], bv[4];
#pragma unroll
            for (int Mt = 0; Mt < 4; Mt++)
                av[Mt] = *reinterpret_cast<const bf16x8*>(
                    (const char*)smem + vb[dx] + dy*HROWSTR + Mt*1024 + dx*64);
#pragma unroll
            for (int Nt = 0; Nt < 4; Nt++)
                bv[Nt] = *reinterpret_cast<const bf16x8*>(wb + tap*4096 + Nt*256);
            // Swapped operands: D[row=co-local][col=px-local].
#pragma unroll
            for (int Mt = 0; Mt < 4; Mt++)
#pragma unroll
                for (int Nt = 0; Nt < 4; Nt++)
                    acc[Mt][Nt] = __builtin_amdgcn_mfma_f32_16x16x32_bf16(
                        bv[Nt], av[Mt], acc[Mt][Nt], 0, 0, 0);
        }
    }

    // Epilogue. D layout: col(px-local)=m, row(co-local)=q*4+r.
    int yout = y0 + w;
#pragma unroll
    for (int Nt = 0; Nt < 4; Nt++) {
        float4 bs = *reinterpret_cast<const float4*>(bias + Nt*16 + q*4);
        int co0 = Nt*16 + q*4;
#pragma unroll
        for (int Mt = 0; Mt < 4; Mt++) {
            int px = X0 + Mt*16 + m;
            float v0 = acc[Mt][Nt][0] + bs.x;
            float v1 = acc[Mt][Nt][1] + bs.y;
            float v2 = acc[Mt][Nt][2] + bs.z;
            float v3 = acc[Mt][Nt][3] + bs.w;
            if (MODE == 1) {
                v0 = gelu_fast(v0); v1 = gelu_fast(v1);
                v2 = gelu_fast(v2); v3 = gelu_fast(v3);
                unsigned short* o = (unsigned short*)outp +
                    ((size_t)(n*NPAD + yout + 1)*NPAD + (px + 1))*64 + co0;
                ushort4 pk = make_ushort4(f2bf(v0), f2bf(v1), f2bf(v2), f2bf(v3));
                *reinterpret_cast<ushort4*>(o) = pk;
            } else {
                float* o = (float*)outp +
                    ((size_t)(n*256 + yout)*256 + px)*64 + co0;
                *reinterpret_cast<float4*>(o) = make_float4(v0, v1, v2, v3);
            }
        }
    }
}

extern "C" void kernel_launch(void* const* d_in, const int* in_sizes, int n_in,
                              void* d_out, int out_size, void* d_ws, size_t ws_size,
                              hipStream_t stream)
{
    const float* means = (const float*)d_in[0];
    const float* feats = (const float*)d_in[2];
    const float* intr  = (const float*)d_in[3];
    const float* extr  = (const float*)d_in[4];
    const float* w1    = (const float*)d_in[5];
    const float* b1    = (const float*)d_in[6];
    const float* w2    = (const float*)d_in[7];
    const float* b2    = (const float*)d_in[8];

    char* ws = (char*)d_ws;
    int*            counts = (int*)(ws + O_COUNTS);
    float*          w2c    = (float*)(ws + O_W2C);
    unsigned short* wT     = (unsigned short*)(ws + O_WT);
    int*            meta   = (int*)(ws + O_META);
    unsigned short* fusedP = (unsigned short*)(ws + O_FUSED);
    unsigned short* x1P    = (unsigned short*)(ws + O_X1);

    prep_kernel<<<dim3(96), dim3(256), 0, stream>>>(
        extr, w1, w2, w2c, wT, fusedP, x1P, counts);
    proj_kernel<<<dim3(256, 12), dim3(256), 0, stream>>>(
        means, intr, w2c, meta, counts);
    fuse_kernel<<<dim3(4096, 8), dim3(256), 0, stream>>>(
        feats, meta, counts, fusedP);
    conv_kernel<1><<<dim3(4, 64, 8), dim3(256), 0, stream>>>(
        fusedP, wT, b1, (void*)x1P);
    conv_kernel<2><<<dim3(4, 64, 8), dim3(256), 0, stream>>>(
        x1P, wT + 36864, b2, d_out);
}

// Round 5
// 388.856 us; speedup vs baseline: 2.1121x; 1.0229x over previous
//
#include <hip/hip_runtime.h>
#include <math.h>

// Problem constants
#define HW 65536          // 256*256
#define NPAD 258          // padded spatial dim

typedef short bf16x8 __attribute__((ext_vector_type(8)));
typedef float f32x4  __attribute__((ext_vector_type(4)));

// Workspace layout (bytes)
#define O_COUNTS 0            // 12 * 32 ints = 1536 B
#define O_W2C    2048         // 8 * 16 floats = 512 B
#define O_WT     4096         // 2 convs * 36864 bf16 = 147456 B  [cv][h][tap][q][co][8ci]
#define O_META   151552       // 12 * 65536 ints = 3 MiB
#define O_FUSED  3297280      // 8*258*258*64 bf16 = 68,161,536 B
#define O_X1     71458816     // same size

// Conv LDS: ONE half-channel tile: 6 rows x 66 px x 64 B (32 ci).
#define HROWB   4224              // 66 px * 64 B
#define HROWSTR 4240
#define HBUFB   (6 * HROWSTR)     // 25440 B

__device__ __forceinline__ unsigned short f2bf(float f) {
    unsigned int u = __float_as_uint(f);
    u += 0x7FFFu + ((u >> 16) & 1u);   // round-to-nearest-even
    return (unsigned short)(u >> 16);
}

// Pack two f32 -> two bf16 in one u32 (RNE), single instruction.
__device__ __forceinline__ unsigned int cvt_pk_bf16(float lo, float hi) {
    unsigned int r;
    asm("v_cvt_pk_bf16_f32 %0, %1, %2" : "=v"(r) : "v"(lo), "v"(hi));
    return r;
}

// Fast erf-based GELU (Abramowitz-Stegun 7.1.26, |err_erf| <= 1.5e-7).
__device__ __forceinline__ float gelu_fast(float v) {
    float x  = v * 0.70710678118654752f;
    float ax = fabsf(x);
    float t  = __builtin_amdgcn_rcpf(fmaf(0.3275911f, ax, 1.0f));
    float p  = fmaf(t, 1.061405429f, -1.453152027f);
    p = fmaf(t, p, 1.421413741f);
    p = fmaf(t, p, -0.284496736f);
    p = fmaf(t, p, 0.254829592f);
    p = p * t;
    float e   = __expf(-x * x);
    float era = fmaf(-p, e, 1.0f);
    float er  = copysignf(era, x);
    return 0.5f * v * (1.0f + er);
}

// ---------------------------------------------------------------------------
// Prep: invert extrinsics, build bf16 weight fragment image [h][tap][q][co][8ci],
// zero padded-buffer borders, zero counts
// ---------------------------------------------------------------------------
__global__ __launch_bounds__(256) void prep_kernel(
    const float* __restrict__ extr, const float* __restrict__ w1,
    const float* __restrict__ w2, float* __restrict__ w2c,
    unsigned short* __restrict__ wT, unsigned short* __restrict__ fusedP,
    unsigned short* __restrict__ x1P, int* __restrict__ counts)
{
    int tid = blockIdx.x * blockDim.x + threadIdx.x;
    int nth = gridDim.x * blockDim.x;

    if (blockIdx.x == 0) {
        if (threadIdx.x < 8) {
            float a[4][8];
            const float* E = extr + threadIdx.x * 16;
            for (int r = 0; r < 4; r++)
                for (int c = 0; c < 4; c++) {
                    a[r][c] = E[r*4 + c];
                    a[r][4+c] = (r == c) ? 1.0f : 0.0f;
                }
            for (int col = 0; col < 4; col++) {
                int piv = col; float bm = fabsf(a[col][col]);
                for (int r = col+1; r < 4; r++) {
                    float v = fabsf(a[r][col]);
                    if (v > bm) { bm = v; piv = r; }
                }
                if (piv != col)
                    for (int c = 0; c < 8; c++) { float t = a[col][c]; a[col][c] = a[piv][c]; a[piv][c] = t; }
                float f = 1.0f / a[col][col];
                for (int c = 0; c < 8; c++) a[col][c] *= f;
                for (int r = 0; r < 4; r++) if (r != col) {
                    float f2 = a[r][col];
                    for (int c = 0; c < 8; c++) a[r][c] -= f2 * a[col][c];
                }
            }
            float* O = w2c + threadIdx.x * 16;
            for (int r = 0; r < 4; r++)
                for (int c = 0; c < 4; c++) O[r*4+c] = a[r][4+c];
        }
    }

    // Zero padded count slots (12 * 32 ints)
    for (int i = tid; i < 384; i += nth) counts[i] = 0;

    // Weight fragment image: 2 convs * [h2][tap9][q4][co64][j8]
    for (int e = tid; e < 73728; e += nth) {
        int t = e;
        int j  = t & 7;  t >>= 3;
        int co = t & 63; t >>= 6;
        int q  = t & 3;  t >>= 2;
        int tap = t % 9; t /= 9;
        int h  = t & 1;  int cv = t >> 1;
        int ci = h*32 + q*8 + j;
        int ky = tap / 3, kx = tap % 3;
        const float* wsrc = cv ? w2 : w1;
        float v = wsrc[((co*64 + ci)*3 + ky)*3 + kx];
        wT[cv*36864 + ((((h*9 + tap)*4 + q)*64 + co)*8 + j)] = f2bf(v);
    }

    // Zero borders of both padded buffers
    for (int u = tid; u < 2*8*1028*8; u += nth) {
        int t = u;
        int ch   = t & 7;    t >>= 3;
        int cell = t % 1028; t /= 1028;
        int n    = t & 7;    int buf = t >> 3;
        int y, x;
        if      (cell < 258) { y = 0;   x = cell; }
        else if (cell < 516) { y = 257; x = cell - 258; }
        else if (cell < 772) { y = cell - 516 + 1; x = 0; }
        else                 { y = cell - 772 + 1; x = 257; }
        unsigned short* p = (buf ? x1P : fusedP) +
            (((size_t)(n*NPAD + y)*NPAD + x)*64 + ch*8);
        *reinterpret_cast<uint4*>(p) = make_uint4(0u, 0u, 0u, 0u);
    }
}

// ---------------------------------------------------------------------------
// Projection: per (b, j->k) pair, compute mask|idx per point + valid counts.
// ---------------------------------------------------------------------------
__global__ __launch_bounds__(256) void proj_kernel(
    const float* __restrict__ means, const float* __restrict__ intr,
    const float* __restrict__ w2c, int* __restrict__ meta,
    int* __restrict__ counts)
{
    const int jt[6] = {0,1,1,2,2,3};
    const int kt[6] = {1,0,2,1,3,2};
    int s = blockIdx.y;            // 0..11
    int b = s / 6, p = s % 6;
    int j = jt[p], k = kt[p];
    int i = blockIdx.x * 256 + threadIdx.x;

    __shared__ int bcnt;
    if (threadIdx.x == 0) bcnt = 0;
    __syncthreads();

    const float* mp = means + ((size_t)(b*4 + j)*HW + i)*3;
    float x = mp[0], y = mp[1], z = mp[2];
    const float* M = w2c + (b*4 + k)*16;
    const float* I = intr + (b*4 + k)*9;

    float cx = fmaf(M[2],  z, fmaf(M[1], y, M[0]*x)) + M[3];
    float cy = fmaf(M[6],  z, fmaf(M[5], y, M[4]*x)) + M[7];
    float cz = fmaf(M[10], z, fmaf(M[9], y, M[8]*x)) + M[11];

    bool vz = cz > 1e-8f;
    float zi = cz + 1e-8f;
    float sx = cx / zi, sy = cy / zi, sz = cz / zi;
    float nx = fmaf(I[2], sz, fmaf(I[1], sy, I[0]*sx));
    float ny = fmaf(I[5], sz, fmaf(I[4], sy, I[3]*sx));

    int px = (int)floorf(nx * 256.0f);
    int py = (int)floorf(ny * 256.0f);
    bool mask = (nx >= 0.0f) && (nx < 1.0f) && (ny >= 0.0f) && (ny < 1.0f) && vz;
    int pxc = min(max(px, 0), 255);
    int pyc = min(max(py, 0), 255);
    int idx = pyc*256 + pxc;
    meta[(size_t)s*HW + i] = idx | (mask ? (int)0x80000000 : 0);

    unsigned long long bal = __ballot(mask ? 1 : 0);
    if ((threadIdx.x & 63) == 0)
        atomicAdd(&bcnt, (int)__popcll(bal));
    __syncthreads();
    if (threadIdx.x == 0)
        atomicAdd(counts + s*32, bcnt);
}

// ---------------------------------------------------------------------------
// Fusion: acc = feats_j + sum_k scale_k * masked_gather(feats_k); /norm; bf16
// ---------------------------------------------------------------------------
__global__ __launch_bounds__(256) void fuse_kernel(
    const float* __restrict__ feats, const int* __restrict__ meta,
    const int* __restrict__ counts, unsigned short* __restrict__ fusedP)
{
    const int nsl[4]    = {1, 2, 2, 1};
    const int slt[4][2] = {{0,0},{1,2},{3,4},{5,5}};
    const int kvw[4][2] = {{1,1},{0,2},{1,3},{2,2}};

    int bj = blockIdx.y;           // n = b*4 + j
    int b = bj >> 2, j = bj & 3;
    int pt = blockIdx.x * 16 + (threadIdx.x >> 4);
    int cg = threadIdx.x & 15;

    const float4* fj = reinterpret_cast<const float4*>(
        feats + ((size_t)bj*HW + pt)*64) + cg;
    float4 acc = *fj;
    float norm = 1.0f;
    int ns = nsl[j];
    for (int e = 0; e < 2; e++) {
        if (e < ns) {
            int p = slt[j][e], k = kvw[j][e];
            int s = b*6 + p;
            float scale = 0.1f * (float)counts[s*32] / 65536.0f;
            int mt = meta[(size_t)s*HW + pt];
            if (mt < 0) {
                int idx = mt & 0xFFFF;
                const float4* g = reinterpret_cast<const float4*>(
                    feats + ((size_t)(b*4 + k)*HW + idx)*64) + cg;
                float4 gv = *g;
                acc.x += scale * gv.x; acc.y += scale * gv.y;
                acc.z += scale * gv.z; acc.w += scale * gv.w;
            }
            norm += scale;
        }
    }
    float rn = 1.0f / norm;

    int yy = pt >> 8, xx = pt & 255;
    unsigned short* op = fusedP +
        (((size_t)bj*NPAD + (yy+1))*NPAD + (xx+1))*64 + cg*4;
    uint2 o = make_uint2(cvt_pk_bf16(acc.x*rn, acc.y*rn),
                         cvt_pk_bf16(acc.z*rn, acc.w*rn));
    *reinterpret_cast<uint2*>(op) = o;
}

// ---------------------------------------------------------------------------
// 3x3 conv: block = 256 thr (4 waves), tile = 4 output rows x 64 px x 64 co.
// Channels split into 2 halves of 32 ci; ONE 25.4 KB LDS buffer used twice.
//
// Round-5 changes (issue-overhead + locality theory):
//  - XCD-bijective flat-block remap: 2048 blocks, XCD k <- image k (256 tiles)
//    so all halo-row reuse is XCD-local L2 (FETCH 1.52x -> ~1.05x ideal).
//  - Weight loads: wave-uniform pointer (SGPR base, SALU per-tap advance) +
//    one per-lane voffset + Nt*256 imm -> ~0 VALU per load (was 2/load).
//  - Epilogue: one per-lane byte base, per-Mt SALU-advanced, Nt*{32,64} imm
//    stores; bf16 pack via v_cvt_pk_bf16_f32 (1 instr / 2 values).
//  - s_setprio(1) around the MFMA tap loops (T5).
//
// Half-tile swizzle: LDS slot (px,c) holds global chunk c ^ ((px>>1)&3);
// staging keeps LDS dest linear and pre-swizzles the GLOBAL source address.
// MFMA operands swapped (weights=A, pixels=B): lane's D holds 4 contiguous
// co per px -> vectorized 8B/16B stores. NOTE: no min-waves in launch_bounds
// (round 3: pinning forced VGPR 40 + acc spills to scratch, 3.5x slower).
// ---------------------------------------------------------------------------
template<int MODE>
__global__ __launch_bounds__(256) void conv_kernel(
    const unsigned short* __restrict__ in, const unsigned short* __restrict__ wT,
    const float* __restrict__ bias, void* __restrict__ outp)
{
    __shared__ unsigned short smem[HBUFB / 2];   // 25440 B

    // XCD-bijective remap: fid -> wg such that XCD (fid&7) gets one image.
    int fid = blockIdx.x;
    int wg  = ((fid & 7) << 8) + (fid >> 3);
    int n   = wg >> 8;             // image 0..7
    int rem = wg & 255;
    int y0  = (rem >> 2) << 2;     // first output row (unpadded), x fastest
    int X0  = (rem & 3) << 6;      // first output px (unpadded)

    int w  = threadIdx.x >> 6;     // wave id: output row y0+w
    int lane = threadIdx.x & 63;
    int m = lane & 15, q = lane >> 4;

    // Staging per-lane source offsets (relative to a (row, h) strip base).
    int srcl = ((lane >> 2) * 128) + ((((lane & 3) ^ ((lane >> 3) & 3)) & 3) << 4);
    int tsrcl = 8192 + ((lane >> 2) * 128) + ((lane & 3) << 4);

    // ds_read per-lane bases (one per dx; q fixed per lane so XOR collapses).
    int vb[3];
#pragma unroll
    for (int dx = 0; dx < 3; dx++)
        vb[dx] = w*HROWSTR + m*64 + (((q ^ (((m + dx) >> 1) & 3)) & 3) << 4);

    // Per-lane weight fragment offset (bytes); tap/Nt handled by uniform
    // pointer + imm so the loads are saddr-form with zero per-load VALU.
    int wvoff = q*1024 + m*16;

    f32x4 acc[4][4];
#pragma unroll
    for (int a = 0; a < 4; a++)
#pragma unroll
        for (int bq = 0; bq < 4; bq++)
            acc[a][bq] = (f32x4){0.f, 0.f, 0.f, 0.f};

#pragma unroll
    for (int h = 0; h < 2; h++) {
        if (h) __syncthreads();    // all waves done reading half 0

        // Stage half-channel h of 6 padded rows [y0..y0+5] x px [X0..X0+65]
        const char* gb = (const char*)in +
            (((size_t)(n*NPAD) + y0) * NPAD + X0) * 128 + h*64;
        for (int ri = w; ri < 6; ri += 4) {
            const char* g = gb + (size_t)ri * (NPAD*128);
            char* l = (char*)smem + ri*HROWSTR;
#pragma unroll
            for (int i = 0; i < 4; i++)
                __builtin_amdgcn_global_load_lds(
                    (const __attribute__((address_space(1))) unsigned int*)(g + i*2048 + srcl),
                    (__attribute__((address_space(3))) unsigned int*)(l + i*1024 + (size_t)lane*16),
                    16, 0, 0);
            if (lane < 8)
                __builtin_amdgcn_global_load_lds(
                    (const __attribute__((address_space(1))) unsigned int*)(g + tsrcl),
                    (__attribute__((address_space(3))) unsigned int*)(l + 4096 + (size_t)lane*16),
                    16, 0, 0);
        }
        __syncthreads();

        // 9 taps of this half (K=32 per tap -> 1 MFMA per (Mt,Nt))
        const char* wbase = (const char*)wT + h*36864;   // wave-uniform
        __builtin_amdgcn_s_setprio(1);
#pragma unroll
        for (int tap = 0; tap < 9; tap++) {
            int dy = tap/3, dx = tap%3;
            const char* wtap = wbase + tap*4096;         // uniform SALU add
            bf16x8 av[4], bv[4];
#pragma unroll
            for (int Mt = 0; Mt < 4; Mt++)
                av[Mt] = *reinterpret_cast<const bf16x8*>(
                    (const char*)smem + vb[dx] + dy*HROWSTR + Mt*1024 + dx*64);
#pragma unroll
            for (int Nt = 0; Nt < 4; Nt++)
                bv[Nt] = *reinterpret_cast<const bf16x8*>(wtap + wvoff + Nt*256);
            // Swapped operands: D[row=co-local][col=px-local].
#pragma unroll
            for (int Mt = 0; Mt < 4; Mt++)
#pragma unroll
                for (int Nt = 0; Nt < 4; Nt++)
                    acc[Mt][Nt] = __builtin_amdgcn_mfma_f32_16x16x32_bf16(
                        bv[Nt], av[Mt], acc[Mt][Nt], 0, 0, 0);
        }
        __builtin_amdgcn_s_setprio(0);
    }

    // Epilogue. D layout: col(px-local)=m, row(co-local)=q*4+r.
    // Per-lane base + per-Mt advance + Nt imm offsets.
    int yout = y0 + w;
    float4 bsv[4];
#pragma unroll
    for (int Nt = 0; Nt < 4; Nt++)
        bsv[Nt] = *reinterpret_cast<const float4*>(bias + Nt*16 + q*4);

    if (MODE == 1) {
        char* obase = (char*)outp +
            (((size_t)(n*NPAD + yout + 1))*NPAD + (X0 + 1))*128 + m*128 + q*8;
#pragma unroll
        for (int Mt = 0; Mt < 4; Mt++) {
            char* ob = obase + Mt*2048;
#pragma unroll
            for (int Nt = 0; Nt < 4; Nt++) {
                float v0 = gelu_fast(acc[Mt][Nt][0] + bsv[Nt].x);
                float v1 = gelu_fast(acc[Mt][Nt][1] + bsv[Nt].y);
                float v2 = gelu_fast(acc[Mt][Nt][2] + bsv[Nt].z);
                float v3 = gelu_fast(acc[Mt][Nt][3] + bsv[Nt].w);
                uint2 pk = make_uint2(cvt_pk_bf16(v0, v1), cvt_pk_bf16(v2, v3));
                *reinterpret_cast<uint2*>(ob + Nt*32) = pk;
            }
        }
    } else {
        char* obase = (char*)outp +
            (((size_t)(n*256 + yout))*256 + X0)*256 + m*256 + q*16;
#pragma unroll
        for (int Mt = 0; Mt < 4; Mt++) {
            char* ob = obase + Mt*4096;
#pragma unroll
            for (int Nt = 0; Nt < 4; Nt++) {
                float4 v = make_float4(acc[Mt][Nt][0] + bsv[Nt].x,
                                       acc[Mt][Nt][1] + bsv[Nt].y,
                                       acc[Mt][Nt][2] + bsv[Nt].z,
                                       acc[Mt][Nt][3] + bsv[Nt].w);
                *reinterpret_cast<float4*>(ob + Nt*64) = v;
            }
        }
    }
}

extern "C" void kernel_launch(void* const* d_in, const int* in_sizes, int n_in,
                              void* d_out, int out_size, void* d_ws, size_t ws_size,
                              hipStream_t stream)
{
    const float* means = (const float*)d_in[0];
    const float* feats = (const float*)d_in[2];
    const float* intr  = (const float*)d_in[3];
    const float* extr  = (const float*)d_in[4];
    const float* w1    = (const float*)d_in[5];
    const float* b1    = (const float*)d_in[6];
    const float* w2    = (const float*)d_in[7];
    const float* b2    = (const float*)d_in[8];

    char* ws = (char*)d_ws;
    int*            counts = (int*)(ws + O_COUNTS);
    float*          w2c    = (float*)(ws + O_W2C);
    unsigned short* wT     = (unsigned short*)(ws + O_WT);
    int*            meta   = (int*)(ws + O_META);
    unsigned short* fusedP = (unsigned short*)(ws + O_FUSED);
    unsigned short* x1P    = (unsigned short*)(ws + O_X1);

    prep_kernel<<<dim3(96), dim3(256), 0, stream>>>(
        extr, w1, w2, w2c, wT, fusedP, x1P, counts);
    proj_kernel<<<dim3(256, 12), dim3(256), 0, stream>>>(
        means, intr, w2c, meta, counts);
    fuse_kernel<<<dim3(4096, 8), dim3(256), 0, stream>>>(
        feats, meta, counts, fusedP);
    conv_kernel<1><<<dim3(2048), dim3(256), 0, stream>>>(
        fusedP, wT, b1, (void*)x1P);
    conv_kernel<2><<<dim3(2048), dim3(256), 0, stream>>>(
        x1P, wT + 36864, b2, d_out);
}

// Round 6
// 379.884 us; speedup vs baseline: 2.1620x; 1.0236x over previous
//
#include <hip/hip_runtime.h>
#include <math.h>

// Problem constants
#define HW 65536          // 256*256
#define NPAD 258          // padded spatial dim

typedef short bf16x8 __attribute__((ext_vector_type(8)));
typedef float f32x4  __attribute__((ext_vector_type(4)));

// Workspace layout (bytes)
#define O_COUNTS 0            // 12 * 32 ints = 1536 B
#define O_W2C    2048         // 8 * 16 floats = 512 B
#define O_WT     4096         // 2 convs * 36864 bf16 = 147456 B  [cv][h][tap][q][co][8ci]
#define O_META   151552       // 12 * 65536 ints = 3 MiB
#define O_FUSED  3297280      // 8*258*258*64 bf16 = 68,161,536 B
#define O_X1     71458816     // same size

// Conv LDS: half-channel tile: 6 rows x 66 px x 64 B (32 ci). Two buffers.
#define HROWB   4224              // 66 px * 64 B
#define HROWSTR 4240
#define HBUF    25440             // 6 * HROWSTR, one buffer

__device__ __forceinline__ unsigned short f2bf(float f) {
    unsigned int u = __float_as_uint(f);
    u += 0x7FFFu + ((u >> 16) & 1u);   // round-to-nearest-even
    return (unsigned short)(u >> 16);
}

// Pack two f32 -> two bf16 in one u32 (RNE), single instruction.
__device__ __forceinline__ unsigned int cvt_pk_bf16(float lo, float hi) {
    unsigned int r;
    asm("v_cvt_pk_bf16_f32 %0, %1, %2" : "=v"(r) : "v"(lo), "v"(hi));
    return r;
}

// Fast erf-based GELU (Abramowitz-Stegun 7.1.26, |err_erf| <= 1.5e-7).
__device__ __forceinline__ float gelu_fast(float v) {
    float x  = v * 0.70710678118654752f;
    float ax = fabsf(x);
    float t  = __builtin_amdgcn_rcpf(fmaf(0.3275911f, ax, 1.0f));
    float p  = fmaf(t, 1.061405429f, -1.453152027f);
    p = fmaf(t, p, 1.421413741f);
    p = fmaf(t, p, -0.284496736f);
    p = fmaf(t, p, 0.254829592f);
    p = p * t;
    float e   = __expf(-x * x);
    float era = fmaf(-p, e, 1.0f);
    float er  = copysignf(era, x);
    return 0.5f * v * (1.0f + er);
}

// ---------------------------------------------------------------------------
// Prep: invert extrinsics, build bf16 weight fragment image [h][tap][q][co][8ci],
// zero padded-buffer borders, zero counts
// ---------------------------------------------------------------------------
__global__ __launch_bounds__(256) void prep_kernel(
    const float* __restrict__ extr, const float* __restrict__ w1,
    const float* __restrict__ w2, float* __restrict__ w2c,
    unsigned short* __restrict__ wT, unsigned short* __restrict__ fusedP,
    unsigned short* __restrict__ x1P, int* __restrict__ counts)
{
    int tid = blockIdx.x * blockDim.x + threadIdx.x;
    int nth = gridDim.x * blockDim.x;

    if (blockIdx.x == 0) {
        if (threadIdx.x < 8) {
            float a[4][8];
            const float* E = extr + threadIdx.x * 16;
            for (int r = 0; r < 4; r++)
                for (int c = 0; c < 4; c++) {
                    a[r][c] = E[r*4 + c];
                    a[r][4+c] = (r == c) ? 1.0f : 0.0f;
                }
            for (int col = 0; col < 4; col++) {
                int piv = col; float bm = fabsf(a[col][col]);
                for (int r = col+1; r < 4; r++) {
                    float v = fabsf(a[r][col]);
                    if (v > bm) { bm = v; piv = r; }
                }
                if (piv != col)
                    for (int c = 0; c < 8; c++) { float t = a[col][c]; a[col][c] = a[piv][c]; a[piv][c] = t; }
                float f = 1.0f / a[col][col];
                for (int c = 0; c < 8; c++) a[col][c] *= f;
                for (int r = 0; r < 4; r++) if (r != col) {
                    float f2 = a[r][col];
                    for (int c = 0; c < 8; c++) a[r][c] -= f2 * a[col][c];
                }
            }
            float* O = w2c + threadIdx.x * 16;
            for (int r = 0; r < 4; r++)
                for (int c = 0; c < 4; c++) O[r*4+c] = a[r][4+c];
        }
    }

    // Zero padded count slots (12 * 32 ints)
    for (int i = tid; i < 384; i += nth) counts[i] = 0;

    // Weight fragment image: 2 convs * [h2][tap9][q4][co64][j8]
    for (int e = tid; e < 73728; e += nth) {
        int t = e;
        int j  = t & 7;  t >>= 3;
        int co = t & 63; t >>= 6;
        int q  = t & 3;  t >>= 2;
        int tap = t % 9; t /= 9;
        int h  = t & 1;  int cv = t >> 1;
        int ci = h*32 + q*8 + j;
        int ky = tap / 3, kx = tap % 3;
        const float* wsrc = cv ? w2 : w1;
        float v = wsrc[((co*64 + ci)*3 + ky)*3 + kx];
        wT[cv*36864 + ((((h*9 + tap)*4 + q)*64 + co)*8 + j)] = f2bf(v);
    }

    // Zero borders of both padded buffers
    for (int u = tid; u < 2*8*1028*8; u += nth) {
        int t = u;
        int ch   = t & 7;    t >>= 3;
        int cell = t % 1028; t /= 1028;
        int n    = t & 7;    int buf = t >> 3;
        int y, x;
        if      (cell < 258) { y = 0;   x = cell; }
        else if (cell < 516) { y = 257; x = cell - 258; }
        else if (cell < 772) { y = cell - 516 + 1; x = 0; }
        else                 { y = cell - 772 + 1; x = 257; }
        unsigned short* p = (buf ? x1P : fusedP) +
            (((size_t)(n*NPAD + y)*NPAD + x)*64 + ch*8);
        *reinterpret_cast<uint4*>(p) = make_uint4(0u, 0u, 0u, 0u);
    }
}

// ---------------------------------------------------------------------------
// Projection: per (b, j->k) pair, compute mask|idx per point + valid counts.
// ---------------------------------------------------------------------------
__global__ __launch_bounds__(256) void proj_kernel(
    const float* __restrict__ means, const float* __restrict__ intr,
    const float* __restrict__ w2c, int* __restrict__ meta,
    int* __restrict__ counts)
{
    const int jt[6] = {0,1,1,2,2,3};
    const int kt[6] = {1,0,2,1,3,2};
    int s = blockIdx.y;            // 0..11
    int b = s / 6, p = s % 6;
    int j = jt[p], k = kt[p];
    int i = blockIdx.x * 256 + threadIdx.x;

    __shared__ int bcnt;
    if (threadIdx.x == 0) bcnt = 0;
    __syncthreads();

    const float* mp = means + ((size_t)(b*4 + j)*HW + i)*3;
    float x = mp[0], y = mp[1], z = mp[2];
    const float* M = w2c + (b*4 + k)*16;
    const float* I = intr + (b*4 + k)*9;

    float cx = fmaf(M[2],  z, fmaf(M[1], y, M[0]*x)) + M[3];
    float cy = fmaf(M[6],  z, fmaf(M[5], y, M[4]*x)) + M[7];
    float cz = fmaf(M[10], z, fmaf(M[9], y, M[8]*x)) + M[11];

    bool vz = cz > 1e-8f;
    float zi = cz + 1e-8f;
    float sx = cx / zi, sy = cy / zi, sz = cz / zi;
    float nx = fmaf(I[2], sz, fmaf(I[1], sy, I[0]*sx));
    float ny = fmaf(I[5], sz, fmaf(I[4], sy, I[3]*sx));

    int px = (int)floorf(nx * 256.0f);
    int py = (int)floorf(ny * 256.0f);
    bool mask = (nx >= 0.0f) && (nx < 1.0f) && (ny >= 0.0f) && (ny < 1.0f) && vz;
    int pxc = min(max(px, 0), 255);
    int pyc = min(max(py, 0), 255);
    int idx = pyc*256 + pxc;
    meta[(size_t)s*HW + i] = idx | (mask ? (int)0x80000000 : 0);

    unsigned long long bal = __ballot(mask ? 1 : 0);
    if ((threadIdx.x & 63) == 0)
        atomicAdd(&bcnt, (int)__popcll(bal));
    __syncthreads();
    if (threadIdx.x == 0)
        atomicAdd(counts + s*32, bcnt);
}

// ---------------------------------------------------------------------------
// Fusion: acc = feats_j + sum_k scale_k * masked_gather(feats_k); /norm; bf16
// ---------------------------------------------------------------------------
__global__ __launch_bounds__(256) void fuse_kernel(
    const float* __restrict__ feats, const int* __restrict__ meta,
    const int* __restrict__ counts, unsigned short* __restrict__ fusedP)
{
    const int nsl[4]    = {1, 2, 2, 1};
    const int slt[4][2] = {{0,0},{1,2},{3,4},{5,5}};
    const int kvw[4][2] = {{1,1},{0,2},{1,3},{2,2}};

    int bj = blockIdx.y;           // n = b*4 + j
    int b = bj >> 2, j = bj & 3;
    int pt = blockIdx.x * 16 + (threadIdx.x >> 4);
    int cg = threadIdx.x & 15;

    const float4* fj = reinterpret_cast<const float4*>(
        feats + ((size_t)bj*HW + pt)*64) + cg;
    float4 acc = *fj;
    float norm = 1.0f;
    int ns = nsl[j];
    for (int e = 0; e < 2; e++) {
        if (e < ns) {
            int p = slt[j][e], k = kvw[j][e];
            int s = b*6 + p;
            float scale = 0.1f * (float)counts[s*32] / 65536.0f;
            int mt = meta[(size_t)s*HW + pt];
            if (mt < 0) {
                int idx = mt & 0xFFFF;
                const float4* g = reinterpret_cast<const float4*>(
                    feats + ((size_t)(b*4 + k)*HW + idx)*64) + cg;
                float4 gv = *g;
                acc.x += scale * gv.x; acc.y += scale * gv.y;
                acc.z += scale * gv.z; acc.w += scale * gv.w;
            }
            norm += scale;
        }
    }
    float rn = 1.0f / norm;

    int yy = pt >> 8, xx = pt & 255;
    unsigned short* op = fusedP +
        (((size_t)bj*NPAD + (yy+1))*NPAD + (xx+1))*64 + cg*4;
    uint2 o = make_uint2(cvt_pk_bf16(acc.x*rn, acc.y*rn),
                         cvt_pk_bf16(acc.z*rn, acc.w*rn));
    *reinterpret_cast<uint2*>(op) = o;
}

// ---------------------------------------------------------------------------
// 3x3 conv, 2-tile pipelined: block = 256 thr (4 waves). Each block processes
// TWO y-tiles (fid -> rows y0..y0+3, and fid+1024 -> rows y0+128..y0+131 of
// the SAME image, preserving the XCD map) as 4 half-channel steps with two
// 25.4 KB LDS buffers. Step s: { STAGE(s+1 -> buf p^1); COMPUTE(s, buf p);
// [EPI]; __syncthreads(); } — the barrier's vmcnt(0) drain finds the next
// stage's loads mostly landed (hidden under the 9-tap compute), vs the old
// stage->sync structure that exposed the full ~900-cyc latency 4x per 2 tiles.
// Race audit: buf p^1's last reader was COMPUTE(s-1), fenced by step s-1's
// sync; COMPUTE(s)'s data was staged in step s-1 and drained by that sync.
// Fully unrolled: buffer parity and tile-1 offsets are compile-time, so NO
// extra live VGPR state (the r2 pipeline failure mode).
//
// Half-tile swizzle: LDS slot (px,c∈0..3 of 16B) holds global chunk
// c ^ ((px>>1)&3); staging keeps LDS dest linear (global_load_lds reqt) and
// pre-swizzles the GLOBAL source address. MFMA operands swapped (weights=A,
// pixels=B): lane's D holds 4 contiguous co per px -> vectorized stores.
// Weight loads are wave-uniform-base + per-lane voffset + imm (saddr form).
// NOTE: no min-waves in launch_bounds (r3: pinning spilled acc to scratch).
// ---------------------------------------------------------------------------
template<int MODE>
__global__ __launch_bounds__(256) void conv_kernel(
    const unsigned short* __restrict__ in, const unsigned short* __restrict__ wT,
    const float* __restrict__ bias, void* __restrict__ outp)
{
    __shared__ unsigned short smem[2 * HBUF / 2];   // 50880 B = two buffers

    // XCD-bijective remap: image = fid&7; tile pair (fid, fid+1024) = same
    // image, rows y0 and y0+128.
    int fid = blockIdx.x;
    int wg  = ((fid & 7) << 8) + (fid >> 3);
    int n   = wg >> 8;             // image 0..7
    int rem = wg & 255;
    int y0  = (rem >> 2) << 2;     // first output row of tile0 (0..124)
    int X0  = (rem & 3) << 6;      // first output px

    int w  = threadIdx.x >> 6;     // wave id: output row y0+w
    int lane = threadIdx.x & 63;
    int m = lane & 15, q = lane >> 4;

    // Staging per-lane source offsets (relative to a (row, h) strip base).
    int srcl = ((lane >> 2) * 128) + ((((lane & 3) ^ ((lane >> 3) & 3)) & 3) << 4);
    int tsrcl = 8192 + ((lane >> 2) * 128) + ((lane & 3) << 4);

    // ds_read per-lane bases (one per dx; q fixed per lane so XOR collapses).
    int vb[3];
#pragma unroll
    for (int dx = 0; dx < 3; dx++)
        vb[dx] = w*HROWSTR + m*64 + (((q ^ (((m + dx) >> 1) & 3)) & 3) << 4);

    int wvoff = q*1024 + m*16;     // per-lane weight fragment offset (bytes)

    const char* gb00 = (const char*)in +
        (((size_t)(n*NPAD) + y0) * NPAD + X0) * 128;   // tile0, h handled below

    // Stage half-channel h of tile at row offset row128 into buffer buf.
    auto STAGE = [&](int row128, int h, int buf) {
        const char* gb = gb00 + (size_t)row128 * (NPAD*128) + h*64;
        char* lb = (char*)smem + buf*HBUF;
        for (int ri = w; ri < 6; ri += 4) {
            const char* g = gb + (size_t)ri * (NPAD*128);
            char* l = lb + ri*HROWSTR;
#pragma unroll
            for (int i = 0; i < 4; i++)
                __builtin_amdgcn_global_load_lds(
                    (const __attribute__((address_space(1))) unsigned int*)(g + i*2048 + srcl),
                    (__attribute__((address_space(3))) unsigned int*)(l + i*1024 + (size_t)lane*16),
                    16, 0, 0);
            if (lane < 8)
                __builtin_amdgcn_global_load_lds(
                    (const __attribute__((address_space(1))) unsigned int*)(g + tsrcl),
                    (__attribute__((address_space(3))) unsigned int*)(l + 4096 + (size_t)lane*16),
                    16, 0, 0);
        }
    };

    f32x4 acc[4][4];
    auto ACCZERO = [&]() {
#pragma unroll
        for (int a = 0; a < 4; a++)
#pragma unroll
            for (int bq = 0; bq < 4; bq++)
                acc[a][bq] = (f32x4){0.f, 0.f, 0.f, 0.f};
    };

    // 9 taps of half-channel h from buffer buf (K=32 -> 1 MFMA per (Mt,Nt))
    auto COMPUTE = [&](int h, int buf) {
        const char* sb = (const char*)smem + buf*HBUF;
        const char* wbase = (const char*)wT + h*36864;   // wave-uniform
        __builtin_amdgcn_s_setprio(1);
#pragma unroll
        for (int tap = 0; tap < 9; tap++) {
            int dy = tap/3, dx = tap%3;
            const char* wtap = wbase + tap*4096;
            bf16x8 av[4], bv[4];
#pragma unroll
            for (int Mt = 0; Mt < 4; Mt++)
                av[Mt] = *reinterpret_cast<const bf16x8*>(
                    sb + vb[dx] + dy*HROWSTR + Mt*1024 + dx*64);
#pragma unroll
            for (int Nt = 0; Nt < 4; Nt++)
                bv[Nt] = *reinterpret_cast<const bf16x8*>(wtap + wvoff + Nt*256);
#pragma unroll
            for (int Mt = 0; Mt < 4; Mt++)
#pragma unroll
                for (int Nt = 0; Nt < 4; Nt++)
                    acc[Mt][Nt] = __builtin_amdgcn_mfma_f32_16x16x32_bf16(
                        bv[Nt], av[Mt], acc[Mt][Nt], 0, 0, 0);
        }
        __builtin_amdgcn_s_setprio(0);
    };

    // Epilogue for tile at row offset row128.
    // D layout: col(px-local)=m, row(co-local)=q*4+r.
    auto EPI = [&](int row128) {
        int yout = y0 + row128 + w;
        float4 bsv[4];
#pragma unroll
        for (int Nt = 0; Nt < 4; Nt++)
            bsv[Nt] = *reinterpret_cast<const float4*>(bias + Nt*16 + q*4);
        if (MODE == 1) {
            char* obase = (char*)outp +
                (((size_t)(n*NPAD + yout + 1))*NPAD + (X0 + 1))*128 + m*128 + q*8;
#pragma unroll
            for (int Mt = 0; Mt < 4; Mt++) {
                char* ob = obase + Mt*2048;
#pragma unroll
                for (int Nt = 0; Nt < 4; Nt++) {
                    float v0 = gelu_fast(acc[Mt][Nt][0] + bsv[Nt].x);
                    float v1 = gelu_fast(acc[Mt][Nt][1] + bsv[Nt].y);
                    float v2 = gelu_fast(acc[Mt][Nt][2] + bsv[Nt].z);
                    float v3 = gelu_fast(acc[Mt][Nt][3] + bsv[Nt].w);
                    uint2 pk = make_uint2(cvt_pk_bf16(v0, v1), cvt_pk_bf16(v2, v3));
                    *reinterpret_cast<uint2*>(ob + Nt*32) = pk;
                }
            }
        } else {
            char* obase = (char*)outp +
                (((size_t)(n*256 + yout))*256 + X0)*256 + m*256 + q*16;
#pragma unroll
            for (int Mt = 0; Mt < 4; Mt++) {
                char* ob = obase + Mt*4096;
#pragma unroll
                for (int Nt = 0; Nt < 4; Nt++) {
                    float4 v = make_float4(acc[Mt][Nt][0] + bsv[Nt].x,
                                           acc[Mt][Nt][1] + bsv[Nt].y,
                                           acc[Mt][Nt][2] + bsv[Nt].z,
                                           acc[Mt][Nt][3] + bsv[Nt].w);
                    *reinterpret_cast<float4*>(ob + Nt*64) = v;
                }
            }
        }
    };

    // ---- 4-step pipeline: (t0,h0) (t0,h1) (t1,h0) (t1,h1) ----
    ACCZERO();
    STAGE(0, 0, 0);
    __syncthreads();               // prologue drain (only fully-exposed stage)

    STAGE(0, 1, 1);                // prefetch (t0,h1) -> hidden under compute
    COMPUTE(0, 0);
    __syncthreads();

    STAGE(128, 0, 0);              // prefetch (t1,h0)
    COMPUTE(1, 1);
    EPI(0);
    ACCZERO();
    __syncthreads();

    STAGE(128, 1, 1);              // prefetch (t1,h1)
    COMPUTE(0, 0);
    __syncthreads();

    COMPUTE(1, 1);
    EPI(128);
}

extern "C" void kernel_launch(void* const* d_in, const int* in_sizes, int n_in,
                              void* d_out, int out_size, void* d_ws, size_t ws_size,
                              hipStream_t stream)
{
    const float* means = (const float*)d_in[0];
    const float* feats = (const float*)d_in[2];
    const float* intr  = (const float*)d_in[3];
    const float* extr  = (const float*)d_in[4];
    const float* w1    = (const float*)d_in[5];
    const float* b1    = (const float*)d_in[6];
    const float* w2    = (const float*)d_in[7];
    const float* b2    = (const float*)d_in[8];

    char* ws = (char*)d_ws;
    int*            counts = (int*)(ws + O_COUNTS);
    float*          w2c    = (float*)(ws + O_W2C);
    unsigned short* wT     = (unsigned short*)(ws + O_WT);
    int*            meta   = (int*)(ws + O_META);
    unsigned short* fusedP = (unsigned short*)(ws + O_FUSED);
    unsigned short* x1P    = (unsigned short*)(ws + O_X1);

    prep_kernel<<<dim3(96), dim3(256), 0, stream>>>(
        extr, w1, w2, w2c, wT, fusedP, x1P, counts);
    proj_kernel<<<dim3(256, 12), dim3(256), 0, stream>>>(
        means, intr, w2c, meta, counts);
    fuse_kernel<<<dim3(4096, 8), dim3(256), 0, stream>>>(
        feats, meta, counts, fusedP);
    conv_kernel<1><<<dim3(1024), dim3(256), 0, stream>>>(
        fusedP, wT, b1, (void*)x1P);
    conv_kernel<2><<<dim3(1024), dim3(256), 0, stream>>>(
        x1P, wT + 36864, b2, d_out);
}